// Round 1
// baseline (20356.226 us; speedup 1.0000x reference)
//
#include <hip/hip_runtime.h>
#include <hip/hip_bf16.h>
#include <hip/hip_cooperative_groups.h>

namespace cg = cooperative_groups;

using s16x8 = __attribute__((ext_vector_type(8))) short;   // 8 bf16 (4 VGPRs) MFMA frag
using f32x4 = __attribute__((ext_vector_type(4))) float;   // MFMA accumulator

constexpr int BB = 64;    // batch
constexpr int SS = 512;   // seq len
constexpr int II = 1024;  // input dim
constexpr int HH = 1024;  // hidden dim

__device__ __forceinline__ unsigned short f2bf(float f) {
  unsigned u = __float_as_uint(f);
  unsigned r = u + 0x7fffu + ((u >> 16) & 1u);   // RN-even
  return (unsigned short)(r >> 16);
}
__device__ __forceinline__ float bf2f(unsigned short h) {
  return __uint_as_float(((unsigned)h) << 16);
}

// Pack weights into combined [256 blk][16 rows][2048 K] bf16 hi + lo splits.
// Row r = j*4+g (j = hcol within block 0..3, g = gate i/f/g/o). K: 0..1023 = W_i, 1024..2047 = W_h.
__global__ void __launch_bounds__(256) pack_w(
    const float* __restrict__ wii, const float* __restrict__ whi_,
    const float* __restrict__ wif, const float* __restrict__ whf,
    const float* __restrict__ wig, const float* __restrict__ whg,
    const float* __restrict__ wio, const float* __restrict__ who,
    unsigned short* __restrict__ Whi, unsigned short* __restrict__ Wlo)
{
  size_t idx = ((size_t)blockIdx.x * 256 + threadIdx.x) * 4;  // elem idx in [4096 rows][2048]
  int k   = (int)(idx & 2047);
  int rg  = (int)(idx >> 11);
  int row = rg & 15;
  int blk = rg >> 4;
  int hc  = blk * 4 + (row >> 2);
  int g   = row & 3;
  const float* wi4[4] = {wii, wif, wig, wio};
  const float* wh4[4] = {whi_, whf, whg, who};
  const float* src = (k < 1024) ? (wi4[g] + (size_t)hc * 1024 + k)
                                : (wh4[g] + (size_t)hc * 1024 + (k - 1024));
  float4 v = *(const float4*)src;
  float vv[4] = {v.x, v.y, v.z, v.w};
  unsigned short h_[4], l_[4];
#pragma unroll
  for (int j = 0; j < 4; ++j) {
    unsigned short h = f2bf(vv[j]);
    h_[j] = h;
    l_[j] = f2bf(vv[j] - bf2f(h));   // residual split: removes W quantization error
  }
  *(ushort4*)(Whi + idx) = make_ushort4(h_[0], h_[1], h_[2], h_[3]);
  *(ushort4*)(Wlo + idx) = make_ushort4(l_[0], l_[1], l_[2], l_[3]);
}

// Combined bias per (blk, col): col = j*4+g
__global__ void __launch_bounds__(256) pack_bias(
    const float* __restrict__ bii, const float* __restrict__ bhi,
    const float* __restrict__ bif, const float* __restrict__ bhf,
    const float* __restrict__ big, const float* __restrict__ bhg,
    const float* __restrict__ bio, const float* __restrict__ bho,
    float* __restrict__ biasC)
{
  int cidx = blockIdx.x * 256 + threadIdx.x;  // 0..4095
  int col = cidx & 15, blk = cidx >> 4;
  int hc = blk * 4 + (col >> 2), g = col & 3;
  const float* bi4[4] = {bii, bif, big, bio};
  const float* bh4[4] = {bhi, bhf, bhg, bho};
  biasC[cidx] = bi4[g][hc] + bh4[g][hc];
}

// x [B][S][I] fp32 -> xb [S][B][I] bf16
__global__ void __launch_bounds__(256) conv_x(const float* __restrict__ x,
                                              unsigned short* __restrict__ xb)
{
  int bs = blockIdx.x;
  int b = bs >> 9, s = bs & 511;
  float4 v = *(const float4*)(x + ((size_t)b * 512 + s) * 1024 + threadIdx.x * 4);
  *(ushort4*)(xb + ((size_t)s * 64 + b) * 1024 + threadIdx.x * 4) =
      make_ushort4(f2bf(v.x), f2bf(v.y), f2bf(v.z), f2bf(v.w));
}

// Persistent cooperative LSTM. 256 blocks x 512 threads.
// Block owns 4 h-cols (16 gate rows). Waves: m = wave>>1 (batch 16-row tile), ks = wave&1
// (0 = x-part K 0..1023, 1 = h-part K 1024..2047). One grid.sync per timestep.
template <bool USE_XB>
__global__ void __launch_bounds__(512, 1) lstm_seq(
    const unsigned short* __restrict__ W,   // hi [256][16][2048]; lo at +8388608 elems
    const float* __restrict__ biasC,        // [256][16]
    const unsigned short* __restrict__ xb,  // [S][B][I] bf16 (USE_XB)
    const float* __restrict__ xin,          // [B][S][I] fp32 (!USE_XB)
    unsigned short* __restrict__ hb,        // [2][B][H] bf16 ping-pong
    const float* __restrict__ h0,
    const float* __restrict__ c0,
    float* __restrict__ out)                // hidden_seq [B][S][H], h_f, c_f
{
  __shared__ short Wl[2][16][2048];         // 128 KB: [hi/lo][row][k], XOR-swizzled
  __shared__ float gLds[2][64][17];         // partial gate preacts, padded stride
  __shared__ float biasLds[16];

  const int tid  = threadIdx.x;
  const int blk  = blockIdx.x;
  const int wave = tid >> 6;
  const int lane = tid & 63;
  const int m    = wave >> 1;     // batch tile
  const int ks   = wave & 1;      // K half
  const int arow = m * 16 + (lane & 15);
  const int koff = (lane >> 4) * 8;
  const int brow = lane & 15;
  const int bswz = (brow & 7) << 4;

  // Stage W hi+lo into LDS with 16B XOR swizzle (breaks stride-4096B bank conflict)
  {
    const char* srcH = (const char*)W + (size_t)blk * 65536;
    const char* srcL = (const char*)W + 16777216u + (size_t)blk * 65536;
    char* dstH = (char*)&Wl[0][0][0];
    char* dstL = (char*)&Wl[1][0][0];
#pragma unroll
    for (int it = 0; it < 8; ++it) {
      int boff = it * 8192 + tid * 16;
      int row  = boff >> 12;
      int colb = boff & 4095;
      int dsw  = row * 4096 + (colb ^ ((row & 7) << 4));
      *(int4*)(dstH + dsw) = *(const int4*)(srcH + boff);
      *(int4*)(dstL + dsw) = *(const int4*)(srcL + boff);
    }
  }
  if (tid < 16) biasLds[tid] = biasC[blk * 16 + tid];

  // init h ping-pong buffer 0 from h0; c state lives in a register per (batch, col) thread
  if (tid < 256) {
    int e = blk * 256 + tid;                 // 256 blocks x 256 = 65536 = B*H
    hb[e] = f2bf(h0[e]);
  }
  const int rb_batch = tid >> 2, rb_j = tid & 3;
  float c_reg = 0.f;
  if (tid < 256) c_reg = c0[rb_batch * 1024 + blk * 4 + rb_j];

  cg::grid_group grid = cg::this_grid();
  __syncthreads();
  grid.sync();

  const char* wrow = (const char*)&Wl[0][0][0] + brow * 4096;
  const int kbyte = ks * 2048;

  for (int t = 0; t < SS; ++t) {
    const unsigned short* hcur = hb + (t & 1) * 65536;
    f32x4 accH = {0.f, 0.f, 0.f, 0.f};
    f32x4 accL = {0.f, 0.f, 0.f, 0.f};

    if (USE_XB || ks == 1) {
      const unsigned short* aptr =
          (ks == 0) ? (xb + (size_t)t * 65536 + arow * 1024 + koff)
                    : (hcur + arow * 1024 + koff);
#pragma unroll
      for (int kk = 0; kk < 1024; kk += 32) {
        s16x8 a = *(const s16x8*)(aptr + kk);
        int cb = (kbyte + (kk + koff) * 2) ^ bswz;
        s16x8 bh = *(const s16x8*)(wrow + cb);
        s16x8 bl = *(const s16x8*)(wrow + 65536 + cb);
        accH = __builtin_amdgcn_mfma_f32_16x16x32_bf16(a, bh, accH, 0, 0, 0);
        accL = __builtin_amdgcn_mfma_f32_16x16x32_bf16(a, bl, accL, 0, 0, 0);
      }
    } else {
      // fallback: read fp32 x directly (ws too small for xb)
      const float* xp = xin + ((size_t)arow * 512 + t) * 1024 + koff;
#pragma unroll
      for (int kk = 0; kk < 1024; kk += 32) {
        float4 f0 = *(const float4*)(xp + kk);
        float4 f1 = *(const float4*)(xp + kk + 4);
        s16x8 a;
        a[0] = (short)f2bf(f0.x); a[1] = (short)f2bf(f0.y);
        a[2] = (short)f2bf(f0.z); a[3] = (short)f2bf(f0.w);
        a[4] = (short)f2bf(f1.x); a[5] = (short)f2bf(f1.y);
        a[6] = (short)f2bf(f1.z); a[7] = (short)f2bf(f1.w);
        int cb = ((kk + koff) * 2) ^ bswz;
        s16x8 bh = *(const s16x8*)(wrow + cb);
        s16x8 bl = *(const s16x8*)(wrow + 65536 + cb);
        accH = __builtin_amdgcn_mfma_f32_16x16x32_bf16(a, bh, accH, 0, 0, 0);
        accL = __builtin_amdgcn_mfma_f32_16x16x32_bf16(a, bl, accL, 0, 0, 0);
      }
    }

    // write K-half partials: D row=(lane>>4)*4+r, col=lane&15  [measured m89/m91]
    {
      f32x4 acc = accH + accL;
      int drow = m * 16 + (lane >> 4) * 4;
      int dcol = lane & 15;
#pragma unroll
      for (int r = 0; r < 4; ++r) gLds[ks][drow + r][dcol] = acc[r];
    }
    __syncthreads();

    if (tid < 256) {
      int c0i = rb_j * 4;
      float si = gLds[0][rb_batch][c0i + 0] + gLds[1][rb_batch][c0i + 0] + biasLds[c0i + 0];
      float sf = gLds[0][rb_batch][c0i + 1] + gLds[1][rb_batch][c0i + 1] + biasLds[c0i + 1];
      float sg = gLds[0][rb_batch][c0i + 2] + gLds[1][rb_batch][c0i + 2] + biasLds[c0i + 2];
      float so = gLds[0][rb_batch][c0i + 3] + gLds[1][rb_batch][c0i + 3] + biasLds[c0i + 3];
      float iv = 1.f / (1.f + __expf(-si));
      float fv = 1.f / (1.f + __expf(-sf));
      float gv = tanhf(sg);
      float ov = 1.f / (1.f + __expf(-so));
      c_reg = fv * c_reg + iv * gv;
      float hv = ov * tanhf(c_reg);
      int hcg = blk * 4 + rb_j;
      out[(size_t)rb_batch * (SS * HH) + (size_t)t * HH + hcg] = hv;
      hb[((t + 1) & 1) * 65536 + rb_batch * 1024 + hcg] = f2bf(hv);
      if (t == SS - 1) {
        out[(size_t)BB * SS * HH + rb_batch * 1024 + hcg] = hv;          // h_f
        out[(size_t)BB * SS * HH + 65536 + rb_batch * 1024 + hcg] = c_reg; // c_f
      }
    }
    grid.sync();   // h_{t+1} globally visible before next step
  }
}

extern "C" void kernel_launch(void* const* d_in, const int* in_sizes, int n_in,
                              void* d_out, int out_size, void* d_ws, size_t ws_size,
                              hipStream_t stream) {
  const float* xin = (const float*)d_in[0];
  const float* h0  = (const float*)d_in[1];
  const float* c0  = (const float*)d_in[2];
  const float* wii = (const float*)d_in[3];
  const float* whi = (const float*)d_in[4];
  const float* bii = (const float*)d_in[5];
  const float* bhi = (const float*)d_in[6];
  const float* wif = (const float*)d_in[7];
  const float* whf = (const float*)d_in[8];
  const float* bif = (const float*)d_in[9];
  const float* bhf = (const float*)d_in[10];
  const float* wig = (const float*)d_in[11];
  const float* whg = (const float*)d_in[12];
  const float* big = (const float*)d_in[13];
  const float* bhg = (const float*)d_in[14];
  const float* wio = (const float*)d_in[15];
  const float* who = (const float*)d_in[16];
  const float* bio = (const float*)d_in[17];
  const float* bho = (const float*)d_in[18];
  float* out = (float*)d_out;

  char* ws = (char*)d_ws;
  unsigned short* W     = (unsigned short*)ws;                        // 32 MB (hi+lo)
  float*          biasC = (float*)(ws + 33554432);                    // 16 KB
  unsigned short* hb    = (unsigned short*)(ws + 33554432 + 16384);   // 256 KB
  unsigned short* xb    = (unsigned short*)(ws + 33554432 + 16384 + 262144);  // 64 MB
  const size_t need_full = 33554432ull + 16384 + 262144 + 67108864;
  const bool use_xb = ws_size >= need_full;

  pack_w<<<8192, 256, 0, stream>>>(wii, whi, wif, whf, wig, whg, wio, who,
                                   W, W + 8388608);
  pack_bias<<<16, 256, 0, stream>>>(bii, bhi, bif, bhf, big, bhg, bio, bho, biasC);
  if (use_xb) conv_x<<<32768, 256, 0, stream>>>(xin, xb);

  void* ka[] = {(void*)&W, (void*)&biasC, (void*)&xb, (void*)&xin,
                (void*)&hb, (void*)&h0, (void*)&c0, (void*)&out};
  if (use_xb) {
    hipLaunchCooperativeKernel(reinterpret_cast<const void*>(&lstm_seq<true>),
                               dim3(256), dim3(512), ka, 0, stream);
  } else {
    hipLaunchCooperativeKernel(reinterpret_cast<const void*>(&lstm_seq<false>),
                               dim3(256), dim3(512), ka, 0, stream);
  }
}

// Round 2
// 6356.137 us; speedup vs baseline: 3.2026x; 3.2026x over previous
//
#include <hip/hip_runtime.h>
#include <hip/hip_bf16.h>
#include <hip/hip_cooperative_groups.h>

namespace cg = cooperative_groups;

using s16x8 = __attribute__((ext_vector_type(8))) short;   // 8 bf16 (4 VGPRs) MFMA frag
using f32x4 = __attribute__((ext_vector_type(4))) float;   // MFMA accumulator

constexpr int BB = 64;    // batch
constexpr int SS = 512;   // seq len
constexpr int II = 1024;  // input dim
constexpr int HH = 1024;  // hidden dim

__device__ __forceinline__ unsigned short f2bf(float f) {
  unsigned u = __float_as_uint(f);
  unsigned r = u + 0x7fffu + ((u >> 16) & 1u);   // RN-even
  return (unsigned short)(r >> 16);
}
__device__ __forceinline__ float bf2f(unsigned short h) {
  return __uint_as_float(((unsigned)h) << 16);
}

// ---------------------------------------------------------------------------
// FAST PATH packers: W in MFMA-linear fragment order.
// Wpk[blk 256][hl 2][ks 2][kb 32][lane 64][e 8] bf16.
// lane: n = lane&15 (gate-row within block: n = j*4+g), u = lane>>4.
// element k (within ks-half) = kb*32 + u*8 + e.
// ---------------------------------------------------------------------------
__global__ void __launch_bounds__(256) pack_w_lin(
    const float* __restrict__ wii, const float* __restrict__ whi_,
    const float* __restrict__ wif, const float* __restrict__ whf,
    const float* __restrict__ wig, const float* __restrict__ whg,
    const float* __restrict__ wio, const float* __restrict__ who,
    unsigned short* __restrict__ Wpk)
{
  unsigned f = blockIdx.x * 256 + threadIdx.x;   // frag id, 0..2097151
  int lane = f & 63;
  int kb   = (f >> 6) & 31;
  int ks   = (f >> 11) & 1;
  int hl   = (f >> 12) & 1;
  int blk  = (int)(f >> 13);
  int n = lane & 15, u = lane >> 4;
  int hc = blk * 4 + (n >> 2), g = n & 3;
  int k  = kb * 32 + u * 8;
  const float* wi4[4] = {wii, wif, wig, wio};
  const float* wh4[4] = {whi_, whf, whg, who};
  const float* src = (ks == 0) ? (wi4[g] + (size_t)hc * 1024 + k)
                               : (wh4[g] + (size_t)hc * 1024 + k);
  float4 v0 = *(const float4*)src;
  float4 v1 = *(const float4*)(src + 4);
  float vv[8] = {v0.x, v0.y, v0.z, v0.w, v1.x, v1.y, v1.z, v1.w};
  s16x8 r;
#pragma unroll
  for (int e = 0; e < 8; ++e) {
    unsigned short h = f2bf(vv[e]);
    r[e] = hl ? (short)f2bf(vv[e] - bf2f(h))   // residual split removes W-quant err
              : (short)h;
  }
  *(s16x8*)(Wpk + (size_t)f * 8) = r;
}

// Combined bias per (blk, col): col = j*4+g
__global__ void __launch_bounds__(256) pack_bias(
    const float* __restrict__ bii, const float* __restrict__ bhi,
    const float* __restrict__ bif, const float* __restrict__ bhf,
    const float* __restrict__ big, const float* __restrict__ bhg,
    const float* __restrict__ bio, const float* __restrict__ bho,
    float* __restrict__ biasC)
{
  int cidx = blockIdx.x * 256 + threadIdx.x;  // 0..4095
  int col = cidx & 15, blk = cidx >> 4;
  int hc = blk * 4 + (col >> 2), g = col & 3;
  const float* bi4[4] = {bii, bif, big, bio};
  const float* bh4[4] = {bhi, bhf, bhg, bho};
  biasC[cidx] = bi4[g][hc] + bh4[g][hc];
}

// x [B][S][I] fp32 -> xb [S][B][I] bf16
__global__ void __launch_bounds__(256) conv_x(const float* __restrict__ x,
                                              unsigned short* __restrict__ xb)
{
  int bs = blockIdx.x;
  int b = bs >> 9, s = bs & 511;
  float4 v = *(const float4*)(x + ((size_t)b * 512 + s) * 1024 + threadIdx.x * 4);
  *(ushort4*)(xb + ((size_t)s * 64 + b) * 1024 + threadIdx.x * 4) =
      make_ushort4(f2bf(v.x), f2bf(v.y), f2bf(v.z), f2bf(v.w));
}

// ---------------------------------------------------------------------------
// Fence-free device barrier. Counters memset to 0 per launch (hipMemsetAsync).
// Arrival: relaxed agent atomicAdd (h data already agent-visible: sc1 stores +
// the leading __syncthreads' vmcnt(0) drain). Spin: relaxed agent load.
// No buffer_inv / buffer_wbl2 anywhere -> L2 stays hot across steps.
// Readers never need invalidation: h buffer rotates (fresh addresses).
// ---------------------------------------------------------------------------
__device__ __forceinline__ void gbar(int* c) {
  __syncthreads();   // all block work done; every thread's vmcnt drained
  if (threadIdx.x == 0) {
    __hip_atomic_fetch_add(c, 1, __ATOMIC_RELAXED, __HIP_MEMORY_SCOPE_AGENT);
    while (__hip_atomic_load(c, __ATOMIC_RELAXED, __HIP_MEMORY_SCOPE_AGENT) < 256)
      __builtin_amdgcn_s_sleep(1);
  }
  __syncthreads();
  asm volatile("" ::: "memory");   // no compiler reordering across the barrier
}

// ---------------------------------------------------------------------------
// FAST persistent LSTM. 256 blocks x 512 threads, 1 block/CU.
// Block owns 4 h-cols (16 gate rows). wave: m = wave>>1 (batch tile),
// ks = wave&1 (0 = x K-half, 1 = h K-half). Custom barrier per step.
// hseq: rotating [S+1][B][H] bf16 written with agent-scope stores.
// ---------------------------------------------------------------------------
template <bool USE_XB>
__global__ void __launch_bounds__(512, 1) lstm_fast(
    const unsigned short* __restrict__ Wpk,  // [256][2][2][32][64][8] bf16
    const float* __restrict__ biasC,         // [256][16]
    const unsigned short* __restrict__ xb,   // [S][B][I] bf16 (USE_XB)
    const float* __restrict__ xin,           // [B][S][I] fp32 (!USE_XB)
    unsigned short* __restrict__ hseq,       // [S+1][B][H] bf16 rotating
    int* __restrict__ cnt,                   // [S+1] counters, stride 16 ints
    const float* __restrict__ h0,
    const float* __restrict__ c0,
    float* __restrict__ out)                 // hidden_seq [B][S][H], h_f, c_f
{
  __shared__ s16x8 WlV[8192];                // 128 KB, MFMA-linear frags
  __shared__ float gLds[2][64][17];          // K-half partials, padded
  __shared__ float biasLds[16];
  __shared__ short hOutLds[64][4];           // staged h_t+1 for 8B flush

  const int tid  = threadIdx.x;
  const int blk  = blockIdx.x;
  const int wave = tid >> 6, lane = tid & 63;
  const int m = wave >> 1, ks = wave & 1;
  const int arow = m * 16 + (lane & 15);
  const int koff = (lane >> 4) * 8;

  // stage this block's W chunk (linear 128 KB copy; frag order == read order)
  {
    const s16x8* src = (const s16x8*)(Wpk + (size_t)blk * 65536);
#pragma unroll
    for (int it = 0; it < 16; ++it) WlV[it * 512 + tid] = src[it * 512 + tid];
  }
  if (tid < 16) biasLds[tid] = biasC[blk * 16 + tid];

  // init hseq slot 0 from h0 with agent-visible stores
  if (tid < 128) {
    int p = blk * 128 + tid;                 // pair index over B*H/2
    unsigned lo = f2bf(h0[2 * p]), hi = f2bf(h0[2 * p + 1]);
    __hip_atomic_store((unsigned*)(hseq + 2 * p), lo | (hi << 16),
                       __ATOMIC_RELAXED, __HIP_MEMORY_SCOPE_AGENT);
  }
  const int rb_batch = tid >> 2, rb_j = tid & 3;
  float c_reg = 0.f;
  if (tid < 256) c_reg = c0[rb_batch * 1024 + blk * 4 + rb_j];

  gbar(cnt);   // slot 0 globally visible

  const int wfrag = ks * 32 * 64 + lane;     // hi frags; lo at +4096

  for (int t = 0; t < SS; ++t) {
    f32x4 accH = {0.f, 0.f, 0.f, 0.f};
    f32x4 accL = {0.f, 0.f, 0.f, 0.f};

    if (USE_XB || ks == 1) {
      const unsigned short* aptr = (ks == 0)
          ? (xb   + (size_t)t * 65536 + arow * 1024 + koff)
          : (hseq + (size_t)t * 65536 + arow * 1024 + koff);
#pragma unroll
      for (int kb = 0; kb < 32; ++kb) {
        s16x8 a  = *(const s16x8*)(aptr + kb * 32);
        s16x8 bh = WlV[wfrag + kb * 64];
        s16x8 bl = WlV[4096 + wfrag + kb * 64];
        accH = __builtin_amdgcn_mfma_f32_16x16x32_bf16(a, bh, accH, 0, 0, 0);
        accL = __builtin_amdgcn_mfma_f32_16x16x32_bf16(a, bl, accL, 0, 0, 0);
      }
    } else {
      const float* xp = xin + ((size_t)arow * 512 + t) * 1024 + koff;
#pragma unroll
      for (int kb = 0; kb < 32; ++kb) {
        float4 f0 = *(const float4*)(xp + kb * 32);
        float4 f1 = *(const float4*)(xp + kb * 32 + 4);
        s16x8 a;
        a[0] = (short)f2bf(f0.x); a[1] = (short)f2bf(f0.y);
        a[2] = (short)f2bf(f0.z); a[3] = (short)f2bf(f0.w);
        a[4] = (short)f2bf(f1.x); a[5] = (short)f2bf(f1.y);
        a[6] = (short)f2bf(f1.z); a[7] = (short)f2bf(f1.w);
        s16x8 bh = WlV[wfrag + kb * 64];
        s16x8 bl = WlV[4096 + wfrag + kb * 64];
        accH = __builtin_amdgcn_mfma_f32_16x16x32_bf16(a, bh, accH, 0, 0, 0);
        accL = __builtin_amdgcn_mfma_f32_16x16x32_bf16(a, bl, accL, 0, 0, 0);
      }
    }

    // D layout: row=(lane>>4)*4+r (batch), col=lane&15 (gate-row)
    {
      f32x4 acc = accH + accL;
      int drow = m * 16 + (lane >> 4) * 4;
      int dcol = lane & 15;
#pragma unroll
      for (int r = 0; r < 4; ++r) gLds[ks][drow + r][dcol] = acc[r];
    }
    __syncthreads();

    if (tid < 256) {
      int c0i = rb_j * 4;
      float si = gLds[0][rb_batch][c0i + 0] + gLds[1][rb_batch][c0i + 0] + biasLds[c0i + 0];
      float sf = gLds[0][rb_batch][c0i + 1] + gLds[1][rb_batch][c0i + 1] + biasLds[c0i + 1];
      float sg = gLds[0][rb_batch][c0i + 2] + gLds[1][rb_batch][c0i + 2] + biasLds[c0i + 2];
      float so = gLds[0][rb_batch][c0i + 3] + gLds[1][rb_batch][c0i + 3] + biasLds[c0i + 3];
      float iv = 1.f / (1.f + __expf(-si));
      float fv = 1.f / (1.f + __expf(-sf));
      float gv = tanhf(sg);
      float ov = 1.f / (1.f + __expf(-so));
      c_reg = fv * c_reg + iv * gv;
      float hv = ov * tanhf(c_reg);
      int hcg = blk * 4 + rb_j;
      out[(size_t)rb_batch * (SS * HH) + (size_t)t * HH + hcg] = hv;
      hOutLds[rb_batch][rb_j] = (short)f2bf(hv);
      if (t == SS - 1) {
        out[(size_t)BB * SS * HH + rb_batch * 1024 + hcg] = hv;            // h_f
        out[(size_t)BB * SS * HH + 65536 + rb_batch * 1024 + hcg] = c_reg; // c_f
      }
    }
    __syncthreads();

    // flush h_{t+1}: 64 threads x 8B agent-scope stores (coalesced per batch row)
    if (tid < 64) {
      unsigned long long v = *(const unsigned long long*)&hOutLds[tid][0];
      __hip_atomic_store(
          (unsigned long long*)(hseq + (size_t)(t + 1) * 65536 + tid * 1024 + blk * 4),
          v, __ATOMIC_RELAXED, __HIP_MEMORY_SCOPE_AGENT);
    }
    gbar(cnt + (t + 1) * 16);
  }
}

// ---------------------------------------------------------------------------
// LEGACY fallback (round-1, cg::grid.sync) for small ws_size. Unchanged.
// ---------------------------------------------------------------------------
__global__ void __launch_bounds__(256) pack_w(
    const float* __restrict__ wii, const float* __restrict__ whi_,
    const float* __restrict__ wif, const float* __restrict__ whf,
    const float* __restrict__ wig, const float* __restrict__ whg,
    const float* __restrict__ wio, const float* __restrict__ who,
    unsigned short* __restrict__ Whi, unsigned short* __restrict__ Wlo)
{
  size_t idx = ((size_t)blockIdx.x * 256 + threadIdx.x) * 4;
  int k   = (int)(idx & 2047);
  int rg  = (int)(idx >> 11);
  int row = rg & 15;
  int blk = rg >> 4;
  int hc  = blk * 4 + (row >> 2);
  int g   = row & 3;
  const float* wi4[4] = {wii, wif, wig, wio};
  const float* wh4[4] = {whi_, whf, whg, who};
  const float* src = (k < 1024) ? (wi4[g] + (size_t)hc * 1024 + k)
                                : (wh4[g] + (size_t)hc * 1024 + (k - 1024));
  float4 v = *(const float4*)src;
  float vv[4] = {v.x, v.y, v.z, v.w};
  unsigned short h_[4], l_[4];
#pragma unroll
  for (int j = 0; j < 4; ++j) {
    unsigned short h = f2bf(vv[j]);
    h_[j] = h;
    l_[j] = f2bf(vv[j] - bf2f(h));
  }
  *(ushort4*)(Whi + idx) = make_ushort4(h_[0], h_[1], h_[2], h_[3]);
  *(ushort4*)(Wlo + idx) = make_ushort4(l_[0], l_[1], l_[2], l_[3]);
}

__global__ void __launch_bounds__(512, 1) lstm_seq_legacy(
    const unsigned short* __restrict__ W,
    const float* __restrict__ biasC,
    const float* __restrict__ xin,
    unsigned short* __restrict__ hb,
    const float* __restrict__ h0,
    const float* __restrict__ c0,
    float* __restrict__ out)
{
  __shared__ short Wl[2][16][2048];
  __shared__ float gLds[2][64][17];
  __shared__ float biasLds[16];

  const int tid  = threadIdx.x;
  const int blk  = blockIdx.x;
  const int wave = tid >> 6;
  const int lane = tid & 63;
  const int m    = wave >> 1;
  const int ks   = wave & 1;
  const int arow = m * 16 + (lane & 15);
  const int koff = (lane >> 4) * 8;
  const int brow = lane & 15;
  const int bswz = (brow & 7) << 4;

  {
    const char* srcH = (const char*)W + (size_t)blk * 65536;
    const char* srcL = (const char*)W + 16777216u + (size_t)blk * 65536;
    char* dstH = (char*)&Wl[0][0][0];
    char* dstL = (char*)&Wl[1][0][0];
#pragma unroll
    for (int it = 0; it < 8; ++it) {
      int boff = it * 8192 + tid * 16;
      int row  = boff >> 12;
      int colb = boff & 4095;
      int dsw  = row * 4096 + (colb ^ ((row & 7) << 4));
      *(int4*)(dstH + dsw) = *(const int4*)(srcH + boff);
      *(int4*)(dstL + dsw) = *(const int4*)(srcL + boff);
    }
  }
  if (tid < 16) biasLds[tid] = biasC[blk * 16 + tid];
  if (tid < 256) {
    int e = blk * 256 + tid;
    hb[e] = f2bf(h0[e]);
  }
  const int rb_batch = tid >> 2, rb_j = tid & 3;
  float c_reg = 0.f;
  if (tid < 256) c_reg = c0[rb_batch * 1024 + blk * 4 + rb_j];

  cg::grid_group grid = cg::this_grid();
  __syncthreads();
  grid.sync();

  const char* wrow = (const char*)&Wl[0][0][0] + brow * 4096;
  const int kbyte = ks * 2048;

  for (int t = 0; t < SS; ++t) {
    const unsigned short* hcur = hb + (t & 1) * 65536;
    f32x4 accH = {0.f, 0.f, 0.f, 0.f};
    f32x4 accL = {0.f, 0.f, 0.f, 0.f};

    if (ks == 1) {
      const unsigned short* aptr = hcur + arow * 1024 + koff;
#pragma unroll
      for (int kk = 0; kk < 1024; kk += 32) {
        s16x8 a = *(const s16x8*)(aptr + kk);
        int cb = (kbyte + (kk + koff) * 2) ^ bswz;
        s16x8 bh = *(const s16x8*)(wrow + cb);
        s16x8 bl = *(const s16x8*)(wrow + 65536 + cb);
        accH = __builtin_amdgcn_mfma_f32_16x16x32_bf16(a, bh, accH, 0, 0, 0);
        accL = __builtin_amdgcn_mfma_f32_16x16x32_bf16(a, bl, accL, 0, 0, 0);
      }
    } else {
      const float* xp = xin + ((size_t)arow * 512 + t) * 1024 + koff;
#pragma unroll
      for (int kk = 0; kk < 1024; kk += 32) {
        float4 f0 = *(const float4*)(xp + kk);
        float4 f1 = *(const float4*)(xp + kk + 4);
        s16x8 a;
        a[0] = (short)f2bf(f0.x); a[1] = (short)f2bf(f0.y);
        a[2] = (short)f2bf(f0.z); a[3] = (short)f2bf(f0.w);
        a[4] = (short)f2bf(f1.x); a[5] = (short)f2bf(f1.y);
        a[6] = (short)f2bf(f1.z); a[7] = (short)f2bf(f1.w);
        int cb = ((kk + koff) * 2) ^ bswz;
        s16x8 bh = *(const s16x8*)(wrow + cb);
        s16x8 bl = *(const s16x8*)(wrow + 65536 + cb);
        accH = __builtin_amdgcn_mfma_f32_16x16x32_bf16(a, bh, accH, 0, 0, 0);
        accL = __builtin_amdgcn_mfma_f32_16x16x32_bf16(a, bl, accL, 0, 0, 0);
      }
    }

    {
      f32x4 acc = accH + accL;
      int drow = m * 16 + (lane >> 4) * 4;
      int dcol = lane & 15;
#pragma unroll
      for (int r = 0; r < 4; ++r) gLds[ks][drow + r][dcol] = acc[r];
    }
    __syncthreads();

    if (tid < 256) {
      int c0i = rb_j * 4;
      float si = gLds[0][rb_batch][c0i + 0] + gLds[1][rb_batch][c0i + 0] + biasLds[c0i + 0];
      float sf = gLds[0][rb_batch][c0i + 1] + gLds[1][rb_batch][c0i + 1] + biasLds[c0i + 1];
      float sg = gLds[0][rb_batch][c0i + 2] + gLds[1][rb_batch][c0i + 2] + biasLds[c0i + 2];
      float so = gLds[0][rb_batch][c0i + 3] + gLds[1][rb_batch][c0i + 3] + biasLds[c0i + 3];
      float iv = 1.f / (1.f + __expf(-si));
      float fv = 1.f / (1.f + __expf(-sf));
      float gv = tanhf(sg);
      float ov = 1.f / (1.f + __expf(-so));
      c_reg = fv * c_reg + iv * gv;
      float hv = ov * tanhf(c_reg);
      int hcg = blk * 4 + rb_j;
      out[(size_t)rb_batch * (SS * HH) + (size_t)t * HH + hcg] = hv;
      hb[((t + 1) & 1) * 65536 + rb_batch * 1024 + hcg] = f2bf(hv);
      if (t == SS - 1) {
        out[(size_t)BB * SS * HH + rb_batch * 1024 + hcg] = hv;
        out[(size_t)BB * SS * HH + 65536 + rb_batch * 1024 + hcg] = c_reg;
      }
    }
    grid.sync();
  }
}

extern "C" void kernel_launch(void* const* d_in, const int* in_sizes, int n_in,
                              void* d_out, int out_size, void* d_ws, size_t ws_size,
                              hipStream_t stream) {
  const float* xin = (const float*)d_in[0];
  const float* h0  = (const float*)d_in[1];
  const float* c0  = (const float*)d_in[2];
  const float* wii = (const float*)d_in[3];
  const float* whi = (const float*)d_in[4];
  const float* bii = (const float*)d_in[5];
  const float* bhi = (const float*)d_in[6];
  const float* wif = (const float*)d_in[7];
  const float* whf = (const float*)d_in[8];
  const float* bif = (const float*)d_in[9];
  const float* bhf = (const float*)d_in[10];
  const float* wig = (const float*)d_in[11];
  const float* whg = (const float*)d_in[12];
  const float* big = (const float*)d_in[13];
  const float* bhg = (const float*)d_in[14];
  const float* wio = (const float*)d_in[15];
  const float* who = (const float*)d_in[16];
  const float* bio = (const float*)d_in[17];
  const float* bho = (const float*)d_in[18];
  float* out = (float*)d_out;

  char* ws = (char*)d_ws;
  // fast layout
  unsigned short* Wpk   = (unsigned short*)ws;                 // 32 MB
  float*          biasC = (float*)(ws + 33554432);             // 16 KB
  int*            cnt   = (int*)(ws + 33570816);               // 64 KB (513 x 16 ints)
  unsigned short* hseq  = (unsigned short*)(ws + 33636352);    // 513*131072 = 67239936
  unsigned short* xb    = (unsigned short*)(ws + 100876288);   // 64 MB
  const size_t need_fast    = 100876288ull;
  const size_t need_fast_xb = 100876288ull + 67108864ull;      // 167985152

  // legacy layout (round-1)
  unsigned short* Wl_  = (unsigned short*)ws;                  // 32 MB hi+lo
  unsigned short* hb   = (unsigned short*)(ws + 33570816);     // 256 KB

  if (ws_size >= need_fast) {
    const bool use_xb = ws_size >= need_fast_xb;
    pack_w_lin<<<8192, 256, 0, stream>>>(wii, whi, wif, whf, wig, whg, wio, who, Wpk);
    pack_bias<<<16, 256, 0, stream>>>(bii, bhi, bif, bhf, big, bhg, bio, bho, biasC);
    if (use_xb) conv_x<<<32768, 256, 0, stream>>>(xin, xb);
    hipMemsetAsync(cnt, 0, 65536, stream);

    void* ka[] = {(void*)&Wpk, (void*)&biasC, (void*)&xb, (void*)&xin,
                  (void*)&hseq, (void*)&cnt, (void*)&h0, (void*)&c0, (void*)&out};
    if (use_xb) {
      hipLaunchCooperativeKernel(reinterpret_cast<const void*>(&lstm_fast<true>),
                                 dim3(256), dim3(512), ka, 0, stream);
    } else {
      hipLaunchCooperativeKernel(reinterpret_cast<const void*>(&lstm_fast<false>),
                                 dim3(256), dim3(512), ka, 0, stream);
    }
  } else {
    pack_w<<<8192, 256, 0, stream>>>(wii, whi, wif, whf, wig, whg, wio, who,
                                     Wl_, Wl_ + 8388608);
    pack_bias<<<16, 256, 0, stream>>>(bii, bhi, bif, bhf, big, bhg, bio, bho, biasC);
    void* ka[] = {(void*)&Wl_, (void*)&biasC, (void*)&xin,
                  (void*)&hb, (void*)&h0, (void*)&c0, (void*)&out};
    hipLaunchCooperativeKernel(reinterpret_cast<const void*>(&lstm_seq_legacy),
                               dim3(256), dim3(512), ka, 0, stream);
  }
}